// Round 6
// baseline (595.282 us; speedup 1.0000x reference)
//
#include <hip/hip_runtime.h>

using short4_ = short     __attribute__((ext_vector_type(4)));
using short8  = short     __attribute__((ext_vector_type(8)));
using half2v  = _Float16  __attribute__((ext_vector_type(2)));
using half4   = _Float16  __attribute__((ext_vector_type(4)));
using float2_ = float     __attribute__((ext_vector_type(2)));
using float4_ = float     __attribute__((ext_vector_type(4)));

__device__ __forceinline__ unsigned short f2bf(float f) {
  union { float f; unsigned u; } v; v.f = f;
  unsigned r = v.u + 0x7fffu + ((v.u >> 16) & 1u);
  return (unsigned short)(r >> 16);
}
__device__ __forceinline__ float sgprf(float x) {
  return __int_as_float(__builtin_amdgcn_readfirstlane(__float_as_int(x)));
}
__device__ __forceinline__ half2v pkrtz(float a, float b) {
  return __builtin_bit_cast(half2v, __builtin_amdgcn_cvt_pkrtz(a, b));
}
__device__ __forceinline__ half2v lo64(unsigned long long u) {
  return __builtin_bit_cast(half2v, (unsigned)u);
}
__device__ __forceinline__ half2v hi64(unsigned long long u) {
  return __builtin_bit_cast(half2v, (unsigned)(u >> 32));
}
__device__ __forceinline__ unsigned long long pk64(float a, float b, float c, float d) {
  unsigned lo = __builtin_bit_cast(unsigned, pkrtz(a, b));
  unsigned hi = __builtin_bit_cast(unsigned, pkrtz(c, d));
  return (unsigned long long)lo | ((unsigned long long)hi << 32);
}
// LDS-drain + barrier as one unit; does NOT drain vmcnt (prefetch survives).
__device__ __forceinline__ void bar_lds() {
  asm volatile("s_waitcnt lgkmcnt(0)\ns_barrier" ::: "memory");
}

// ---------------- LayerNorm: x fp32 (8192x512) -> xn bf16 ----------------
__global__ __launch_bounds__(256, 4) void ln_kernel(
    const float* __restrict__ x, const float* __restrict__ gamma,
    const float* __restrict__ beta, unsigned short* __restrict__ xn) {
  int w = threadIdx.x >> 6, lane = threadIdx.x & 63;
  int row = blockIdx.x * 4 + w;
  const float4_* xr = (const float4_*)(x + row * 512);
  float4_ v0 = xr[lane * 2], v1 = xr[lane * 2 + 1];
  float s = 0.f, ss = 0.f;
#pragma unroll
  for (int e = 0; e < 4; ++e) { s += v0[e] + v1[e]; ss += v0[e]*v0[e] + v1[e]*v1[e]; }
#pragma unroll
  for (int off = 1; off < 64; off <<= 1) { s += __shfl_xor(s, off); ss += __shfl_xor(ss, off); }
  float mu = s * (1.f/512.f);
  float var = ss * (1.f/512.f) - mu*mu;
  float rs = rsqrtf(var + 1e-5f);
  const float4_* gp = (const float4_*)gamma;
  const float4_* bp = (const float4_*)beta;
  float4_ g0 = gp[lane*2], g1 = gp[lane*2+1], b0 = bp[lane*2], b1 = bp[lane*2+1];
  short8 pk;
#pragma unroll
  for (int e = 0; e < 4; ++e) {
    pk[e]   = (short)f2bf((v0[e]-mu)*rs*g0[e] + b0[e]);
    pk[e+4] = (short)f2bf((v1[e]-mu)*rs*g1[e] + b1[e]);
  }
  *(short8*)&xn[row*512 + lane*8] = pk;
}

// ------------- weights fp32 -> bf16 transposed (B^T layouts) -------------
__global__ __launch_bounds__(256, 4) void wconv(
    const float* __restrict__ Wq, const float* __restrict__ Wkv,
    const float* __restrict__ Wout,
    unsigned short* __restrict__ wt, unsigned short* __restrict__ wot) {
  int t = blockIdx.x * 256 + threadIdx.x;
  if (t < 786432) {
    int k = t / 1536, n = t % 1536;
    float v = (n < 512) ? Wq[k*512 + n] * 0.125f : Wkv[k*1024 + (n - 512)];
    wt[n*512 + k] = f2bf(v);
  } else {
    int t2 = t - 786432;
    int k = t2 >> 9, n = t2 & 511;
    wot[n*512 + k] = f2bf(Wout[k*512 + n]);
  }
}

// ---------------- QKV GEMM: xn(8192x512) @ Wt^T -> Q,K (bf16 b,h,n,64), V^T (f16 b,h,64,n)
__global__ __launch_bounds__(256, 2) void qkv_gemm(
    const unsigned short* __restrict__ A, const unsigned short* __restrict__ Bt,
    unsigned short* __restrict__ Qs, unsigned short* __restrict__ Kb,
    _Float16* __restrict__ Vt) {
  __shared__ unsigned short lA[128*32];
  __shared__ unsigned short lB[128*32];
  int bid = blockIdx.x;
  int tm = bid & 63, tn = bid >> 6;           // 64 x 12
  int m0 = tm * 128, n0 = tn * 128;
  int tid = threadIdx.x, lane = tid & 63, w = tid >> 6;
  int lrow = lane & 15, lgrp = lane >> 4;
  int wr = w >> 1, wc = w & 1;
  int r0 = tid >> 2, c0 = tid & 3;
  float4_ acc[4][4];
#pragma unroll
  for (int mi = 0; mi < 4; ++mi)
#pragma unroll
    for (int ni = 0; ni < 4; ++ni) acc[mi][ni] = (float4_){0.f,0.f,0.f,0.f};

  for (int k0 = 0; k0 < 512; k0 += 32) {
    short8 a0 = *(const short8*)&A[(m0 + r0)*512 + k0 + c0*8];
    short8 a1 = *(const short8*)&A[(m0 + 64 + r0)*512 + k0 + c0*8];
    short8 b0 = *(const short8*)&Bt[(n0 + r0)*512 + k0 + c0*8];
    short8 b1 = *(const short8*)&Bt[(n0 + 64 + r0)*512 + k0 + c0*8];
    __syncthreads();
    *(short8*)&lA[tid*8] = a0; *(short8*)&lA[(tid+256)*8] = a1;
    *(short8*)&lB[tid*8] = b0; *(short8*)&lB[(tid+256)*8] = b1;
    __syncthreads();
    short8 af[4], bfr[4];
#pragma unroll
    for (int mi = 0; mi < 4; ++mi) af[mi]  = *(const short8*)&lA[(wr*64 + mi*16 + lrow)*32 + lgrp*8];
#pragma unroll
    for (int ni = 0; ni < 4; ++ni) bfr[ni] = *(const short8*)&lB[(wc*64 + ni*16 + lrow)*32 + lgrp*8];
#pragma unroll
    for (int mi = 0; mi < 4; ++mi)
#pragma unroll
      for (int ni = 0; ni < 4; ++ni)
        acc[mi][ni] = __builtin_amdgcn_mfma_f32_16x16x32_bf16(af[mi], bfr[ni], acc[mi][ni], 0, 0, 0);
  }
#pragma unroll
  for (int mi = 0; mi < 4; ++mi) {
#pragma unroll
    for (int ni = 0; ni < 4; ++ni) {
      int col = n0 + wc*64 + ni*16 + lrow;
#pragma unroll
      for (int r = 0; r < 4; ++r) {
        int row = m0 + wr*64 + mi*16 + lgrp*4 + r;
        float v = acc[mi][ni][r];
        int b = row >> 11, i = row & 2047;
        if (col < 1024) {
          unsigned short* dst = (col < 512) ? Qs : Kb;
          int c = col & 511;
          dst[(((b<<3) + (c>>6))*2048 + i)*64 + (c & 63)] = f2bf(v);
        } else {
          int c = col - 1024;
          Vt[(((b<<3) + (c>>6))*64 + (c & 63))*2048 + i] = (_Float16)v;
        }
      }
    }
  }
}

// ---------------- fused talking-heads attention, head-per-wave, batched phases ------
// grid 512 = (4 b x 128 i-tiles), 8 waves; wave w = head w.
// pass1: 32 phases x 4 j-tiles, 1 barrier each.
// pass2: 64 phases x 2 j-tiles, ONE barrier each (S_t and P_{t-1} published together;
//        postmix+PV run one phase behind premix). K reg-double-buffered across phases.
__global__ __launch_bounds__(512, 4) void attn_f(
    const unsigned short* __restrict__ Qs, const unsigned short* __restrict__ Kb,
    const _Float16* __restrict__ Vt, const float* __restrict__ mixp,
    const float* __restrict__ mixq, unsigned short* __restrict__ AO) {
  __shared__ unsigned long long lds[4096];       // 32 KB
  int bid = blockIdx.x;
  int b = (bid & 7) >> 1;                        // same-b blocks share an XCD pair
  int it = ((bid >> 3) << 1) | (bid & 1);
  int i0 = it << 4;
  int tid = threadIdx.x, w = tid >> 6, lane = tid & 63;
  int lrow = lane & 15, lgrp = lane >> 4;
  int bh = (b << 3) + w;

  float mp[8];
#pragma unroll
  for (int h = 0; h < 8; ++h) mp[h] = sgprf(mixp[h*8 + w]);
  unsigned mqs[8];
#pragma unroll
  for (int g = 0; g < 8; ++g) {
    float v = mixq[g*8 + w];
    half2v h2 = pkrtz(v, v);
    mqs[g] = (unsigned)__builtin_amdgcn_readfirstlane((int)__builtin_bit_cast(unsigned, h2));
  }

  const unsigned short* qp = &Qs[(bh*2048 + i0 + lrow)*64 + lgrp*8];
  short8 qf0 = *(const short8*)qp;
  short8 qf1 = *(const short8*)(qp + 32);
  const unsigned short* kbase = &Kb[(bh*2048 + lrow)*64 + lgrp*8];
  const _Float16*       vbase = &Vt[(bh*64 + lrow)*2048 + lgrp*4];

  float m_ = -1e30f, l_ = 0.f;

  // ---------------- PASS 1: stats, 4 j-tiles per phase ----------------
  short8 kA[4][2], kB[4][2];
#pragma unroll
  for (int st = 0; st < 4; ++st) {
    const unsigned short* kp = kbase + (st << 10);
    kA[st][0] = *(const short8*)kp; kA[st][1] = *(const short8*)(kp + 32);
  }
  auto p1 = [&](int t, short8 (&kc)[4][2], short8 (&kn)[4][2]) {
#pragma unroll
    for (int st = 0; st < 4; ++st) {
      const unsigned short* kp = kbase + ((((t + 1)*4 + st) & 127) << 10);
      kn[st][0] = *(const short8*)kp; kn[st][1] = *(const short8*)(kp + 32);
    }
    int buf = (t & 1) << 11;
#pragma unroll
    for (int st = 0; st < 4; ++st) {
      float4_ S = {0.f,0.f,0.f,0.f};
      S = __builtin_amdgcn_mfma_f32_16x16x32_bf16(kc[st][0], qf0, S, 0, 0, 0);
      S = __builtin_amdgcn_mfma_f32_16x16x32_bf16(kc[st][1], qf1, S, 0, 0, 0);
      lds[buf + ((w*4 + st) << 6) + lane] = pk64(S[0], S[1], S[2], S[3]);
    }
    bar_lds();
    float sv[16];
#pragma unroll
    for (int st = 0; st < 4; ++st) {
      float s0 = 0.f, s1 = 0.f, s2 = 0.f, s3 = 0.f;
#pragma unroll
      for (int h = 0; h < 8; ++h) {
        unsigned long long u = lds[buf + ((h*4 + st) << 6) + lane];
        half2v a = lo64(u), c = hi64(u);
        s0 = fmaf(mp[h], (float)a[0], s0);
        s1 = fmaf(mp[h], (float)a[1], s1);
        s2 = fmaf(mp[h], (float)c[0], s2);
        s3 = fmaf(mp[h], (float)c[1], s3);
      }
      sv[st*4+0] = s0; sv[st*4+1] = s1; sv[st*4+2] = s2; sv[st*4+3] = s3;
    }
    float tm = sv[0];
#pragma unroll
    for (int e = 1; e < 16; ++e) tm = fmaxf(tm, sv[e]);
    float mn = fmaxf(m_, tm);
    float acc = 0.f;
#pragma unroll
    for (int e = 0; e < 16; ++e) acc += __expf(sv[e] - mn);
    l_ = l_*__expf(m_ - mn) + acc;
    m_ = mn;
  };
  for (int tt = 0; tt < 16; ++tt) { p1(2*tt, kA, kB); p1(2*tt + 1, kB, kA); }

  // merge across the 4 lane-groups (disjoint j)
#pragma unroll
  for (int off = 16; off < 64; off <<= 1) {
    float om = __shfl_xor(m_, off);
    float ol = __shfl_xor(l_, off);
    float mn = fmaxf(m_, om);
    l_ = l_*__expf(m_ - mn) + ol*__expf(om - mn);
    m_ = mn;
  }
  float mm = m_ + __logf(l_);     // exp(s - mm) is exactly normalized

  bar_lds();                      // lds region reuse between passes

  // ---------------- PASS 2: 2 j-tiles per phase, single barrier ----------------
  float4_ ot[4];
#pragma unroll
  for (int dt = 0; dt < 4; ++dt) ot[dt] = (float4_){0.f,0.f,0.f,0.f};
  short8 k2A[2][2], k2B[2][2];
#pragma unroll
  for (int st = 0; st < 2; ++st) {
    const unsigned short* kp = kbase + (st << 10);
    k2A[st][0] = *(const short8*)kp; k2A[st][1] = *(const short8*)(kp + 32);
  }
  unsigned long long pp0 = 0ull, pp1 = 0ull;    // P_{t-1}, zero for warmup

  auto p2 = [&](int t, short8 (&kc)[2][2], short8 (&kn)[2][2]) {
#pragma unroll
    for (int st = 0; st < 2; ++st) {
      const unsigned short* kp = kbase + ((((t + 1)*2 + st) & 127) << 10);
      kn[st][0] = *(const short8*)kp; kn[st][1] = *(const short8*)(kp + 32);
    }
    half4 vf[2][4];                              // V tiles of phase t-1
#pragma unroll
    for (int st = 0; st < 2; ++st) {
      const _Float16* vb = vbase + (((2*t - 2 + st) & 127) << 4);
#pragma unroll
      for (int dt = 0; dt < 4; ++dt) vf[st][dt] = *(const half4*)(vb + dt*16*2048);
    }
    int sb = (t & 1) << 10;
    int pbase = 2048 + ((t & 1) << 10);
#pragma unroll
    for (int st = 0; st < 2; ++st) {
      float4_ S = {0.f,0.f,0.f,0.f};
      S = __builtin_amdgcn_mfma_f32_16x16x32_bf16(kc[st][0], qf0, S, 0, 0, 0);
      S = __builtin_amdgcn_mfma_f32_16x16x32_bf16(kc[st][1], qf1, S, 0, 0, 0);
      lds[sb + ((w*2 + st) << 6) + lane] = pk64(S[0], S[1], S[2], S[3]);
    }
    lds[pbase + ((w*2 + 0) << 6) + lane] = pp0;
    lds[pbase + ((w*2 + 1) << 6) + lane] = pp1;
    bar_lds();
    // premix + exp for phase t -> new pp
#pragma unroll
    for (int st = 0; st < 2; ++st) {
      float s0 = 0.f, s1 = 0.f, s2 = 0.f, s3 = 0.f;
#pragma unroll
      for (int h = 0; h < 8; ++h) {
        unsigned long long u = lds[sb + ((h*2 + st) << 6) + lane];
        half2v a = lo64(u), c = hi64(u);
        s0 = fmaf(mp[h], (float)a[0], s0);
        s1 = fmaf(mp[h], (float)a[1], s1);
        s2 = fmaf(mp[h], (float)c[0], s2);
        s3 = fmaf(mp[h], (float)c[1], s3);
      }
      unsigned long long np = pk64(__expf(s0 - mm), __expf(s1 - mm),
                                   __expf(s2 - mm), __expf(s3 - mm));
      if (st == 0) pp0 = np; else pp1 = np;
    }
    // postmix P_{t-1} + PV
    half2v A00 = (half2v)0, A01 = (half2v)0, A10 = (half2v)0, A11 = (half2v)0;
#pragma unroll
    for (int g = 0; g < 8; ++g) {
      half2v m2 = __builtin_bit_cast(half2v, mqs[g]);
      unsigned long long u0 = lds[pbase + ((g*2 + 0) << 6) + lane];
      unsigned long long u1 = lds[pbase + ((g*2 + 1) << 6) + lane];
      A00 += m2 * lo64(u0); A01 += m2 * hi64(u0);
      A10 += m2 * lo64(u1); A11 += m2 * hi64(u1);
    }
    half4 pb0, pb1;
    pb0[0] = A00[0]; pb0[1] = A00[1]; pb0[2] = A01[0]; pb0[3] = A01[1];
    pb1[0] = A10[0]; pb1[1] = A10[1]; pb1[2] = A11[0]; pb1[3] = A11[1];
#pragma unroll
    for (int dt = 0; dt < 4; ++dt) {
      ot[dt] = __builtin_amdgcn_mfma_f32_16x16x16f16(vf[0][dt], pb0, ot[dt], 0, 0, 0);
      ot[dt] = __builtin_amdgcn_mfma_f32_16x16x16f16(vf[1][dt], pb1, ot[dt], 0, 0, 0);
    }
  };
  for (int tt = 0; tt < 32; ++tt) { p2(2*tt, k2A, k2B); p2(2*tt + 1, k2B, k2A); }

  // drain: publish P_63, postmix, PV with V tiles {126,127}
  {
    int pbase = 2048;                            // (64 & 1) == 0
    lds[pbase + ((w*2 + 0) << 6) + lane] = pp0;
    lds[pbase + ((w*2 + 1) << 6) + lane] = pp1;
    half4 vf[2][4];
#pragma unroll
    for (int st = 0; st < 2; ++st) {
      const _Float16* vb = vbase + ((126 + st) << 4);
#pragma unroll
      for (int dt = 0; dt < 4; ++dt) vf[st][dt] = *(const half4*)(vb + dt*16*2048);
    }
    bar_lds();
    half2v A00 = (half2v)0, A01 = (half2v)0, A10 = (half2v)0, A11 = (half2v)0;
#pragma unroll
    for (int g = 0; g < 8; ++g) {
      half2v m2 = __builtin_bit_cast(half2v, mqs[g]);
      unsigned long long u0 = lds[pbase + ((g*2 + 0) << 6) + lane];
      unsigned long long u1 = lds[pbase + ((g*2 + 1) << 6) + lane];
      A00 += m2 * lo64(u0); A01 += m2 * hi64(u0);
      A10 += m2 * lo64(u1); A11 += m2 * hi64(u1);
    }
    half4 pb0, pb1;
    pb0[0] = A00[0]; pb0[1] = A00[1]; pb0[2] = A01[0]; pb0[3] = A01[1];
    pb1[0] = A10[0]; pb1[1] = A10[1]; pb1[2] = A11[0]; pb1[3] = A11[1];
#pragma unroll
    for (int dt = 0; dt < 4; ++dt) {
      ot[dt] = __builtin_amdgcn_mfma_f32_16x16x16f16(vf[0][dt], pb0, ot[dt], 0, 0, 0);
      ot[dt] = __builtin_amdgcn_mfma_f32_16x16x16f16(vf[1][dt], pb1, ot[dt], 0, 0, 0);
    }
  }

  // epilogue: O[d = dt*16 + lgrp*4 + r][i = lrow] -> AO (b, n, w*64+d) bf16
  unsigned short* ao = &AO[(b*2048 + i0 + lrow)*512 + w*64 + lgrp*4];
#pragma unroll
  for (int dt = 0; dt < 4; ++dt) {
    short4_ pk;
#pragma unroll
    for (int r = 0; r < 4; ++r) pk[r] = (short)f2bf(ot[dt][r]);
    *(short4_*)(ao + dt*16) = pk;
  }
}

// ---------------- out GEMM: AO(8192x512)bf16 @ Wout^T + bout -> fp32 ----------------
__global__ __launch_bounds__(256, 2) void out_gemm(
    const unsigned short* __restrict__ A, const unsigned short* __restrict__ Bt,
    const float* __restrict__ bout, float* __restrict__ out) {
  __shared__ unsigned short lA[128*32];
  __shared__ unsigned short lB[128*32];
  int bid = blockIdx.x;
  int tm = bid & 63, tn = bid >> 6;           // 64 x 4
  int m0 = tm * 128, n0 = tn * 128;
  int tid = threadIdx.x, lane = tid & 63, w = tid >> 6;
  int lrow = lane & 15, lgrp = lane >> 4;
  int wr = w >> 1, wc = w & 1;
  int r0 = tid >> 2, c0 = tid & 3;
  float4_ acc[4][4];
#pragma unroll
  for (int mi = 0; mi < 4; ++mi)
#pragma unroll
    for (int ni = 0; ni < 4; ++ni) acc[mi][ni] = (float4_){0.f,0.f,0.f,0.f};

  for (int k0 = 0; k0 < 512; k0 += 32) {
    short8 a0 = *(const short8*)&A[(m0 + r0)*512 + k0 + c0*8];
    short8 a1 = *(const short8*)&A[(m0 + 64 + r0)*512 + k0 + c0*8];
    short8 b0 = *(const short8*)&Bt[(n0 + r0)*512 + k0 + c0*8];
    short8 b1 = *(const short8*)&Bt[(n0 + 64 + r0)*512 + k0 + c0*8];
    __syncthreads();
    *(short8*)&lA[tid*8] = a0; *(short8*)&lA[(tid+256)*8] = a1;
    *(short8*)&lB[tid*8] = b0; *(short8*)&lB[(tid+256)*8] = b1;
    __syncthreads();
    short8 af[4], bfr[4];
#pragma unroll
    for (int mi = 0; mi < 4; ++mi) af[mi]  = *(const short8*)&lA[(wr*64 + mi*16 + lrow)*32 + lgrp*8];
#pragma unroll
    for (int ni = 0; ni < 4; ++ni) bfr[ni] = *(const short8*)&lB[(wc*64 + ni*16 + lrow)*32 + lgrp*8];
#pragma unroll
    for (int mi = 0; mi < 4; ++mi)
#pragma unroll
      for (int ni = 0; ni < 4; ++ni)
        acc[mi][ni] = __builtin_amdgcn_mfma_f32_16x16x32_bf16(af[mi], bfr[ni], acc[mi][ni], 0, 0, 0);
  }
#pragma unroll
  for (int mi = 0; mi < 4; ++mi)
#pragma unroll
    for (int ni = 0; ni < 4; ++ni) {
      int col = n0 + wc*64 + ni*16 + lrow;
      float bb = bout[col];
#pragma unroll
      for (int r = 0; r < 4; ++r) {
        int row = m0 + wr*64 + mi*16 + lgrp*4 + r;
        out[row*512 + col] = acc[mi][ni][r] + bb;
      }
    }
}

extern "C" void kernel_launch(void* const* d_in, const int* in_sizes, int n_in,
                              void* d_out, int out_size, void* d_ws, size_t ws_size,
                              hipStream_t stream) {
  (void)in_sizes; (void)n_in; (void)out_size; (void)ws_size;
  const float* x     = (const float*)d_in[0];
  const float* gamma = (const float*)d_in[1];
  const float* beta  = (const float*)d_in[2];
  const float* Wq    = (const float*)d_in[3];
  const float* Wkv   = (const float*)d_in[4];
  const float* mixp  = (const float*)d_in[5];
  const float* mixq  = (const float*)d_in[6];
  const float* Wout  = (const float*)d_in[7];
  const float* bout  = (const float*)d_in[8];
  float* out = (float*)d_out;

  unsigned short* xn  = (unsigned short*)d_ws;      // 4,194,304 bf16
  unsigned short* wt  = xn  + 4194304;              // 786,432 bf16
  unsigned short* wot = wt  + 786432;               // 262,144 bf16
  unsigned short* Qs  = wot + 262144;               // 4,194,304 bf16 (b,h,n,64)
  unsigned short* Kb  = Qs  + 4194304;              // 4,194,304 bf16 (b,h,n,64)
  _Float16*       Vt  = (_Float16*)(Kb + 4194304);  // 4,194,304 f16  (b,h,64,n)
  unsigned short* AO  = (unsigned short*)(Vt + 4194304); // 4,194,304 bf16 (b,n,512)

  ln_kernel<<<2048, 256, 0, stream>>>(x, gamma, beta, xn);
  wconv<<<4096, 256, 0, stream>>>(Wq, Wkv, Wout, wt, wot);
  qkv_gemm<<<768, 256, 0, stream>>>(xn, wt, Qs, Kb, Vt);
  attn_f<<<512, 512, 0, stream>>>(Qs, Kb, Vt, mixp, mixq, AO);
  out_gemm<<<256, 256, 0, stream>>>(AO, wot, bout, out);
}